// Round 6
// baseline (322.171 us; speedup 1.0000x reference)
//
#include <hip/hip_runtime.h>

#define NB   256      // batch
#define NIN  1152
#define NOUT 10
#define NCH  12       // chunks per batch
#define KST  3        // k-steps per chunk; block covers KST*5*256 = 3840 float4 = 60 KB

// Dense-streaming routing via b-linearity: b^(r)_i = u_i . V_r, V_r = sum_{r'<r} v_r'.
// Pass kernel: block = (bb, chunk). 256 threads read contiguous float4s.
//   float4 index F = bb*46080 + c*3840 + k*1280 + j*256 + t  (j<5, k<KST)
//   p = F>>2 = (i*10+oo); q = F&3 = t&3; p0 = t>>2; oo = (p0+4j)%10 (indep of c,k).
//   Quad (lanes 4a..4a+3) owns one (i,oo): dot(u_i,V) via 2 shfl_xor; e=exp(dot);
//   per-lane slot j accumulates (Z_j, S4_j). Block LDS-reduce -> partials in ws.
// Combine kernel: per bb, 40 lanes (oo,q): sum chunk partials, s=S/Z, squash,
//   V_{r+1} = V_r + v_r (or write out at r=2).
// No softmax max-subtraction: |V|<=~1, |u| ~4 => |dot| <~ 10, exp safe in fp32;
// partials stay linear (plain sums), threshold 8.6e-4 >> expected ~1e-4.

template<int MODE>  // 0: uniform weights (e=1, V unused); 1: e=exp(u.V)
__global__ __launch_bounds__(256)
void pass_kernel(const float* __restrict__ u_hat, const float* __restrict__ V,
                 float* __restrict__ P) {
    __shared__ float red[256 * 5 * 5];   // [t][j][{Z,Sx,Sy,Sz,Sw}]

    const int t  = threadIdx.x;
    const int q  = t & 3;
    const int p0 = t >> 2;
    const int bb = blockIdx.x / NCH;
    const int c  = blockIdx.x % NCH;

    float4 Vq[5];
#pragma unroll
    for (int j = 0; j < 5; ++j) {
        if (MODE) {
            const int oo = (p0 + 4 * j) % 10;
            Vq[j] = *reinterpret_cast<const float4*>(V + ((bb * NOUT + oo) * 16) + q * 4);
        }
    }

    float  Z[5];
    float4 S[5];
#pragma unroll
    for (int j = 0; j < 5; ++j) { Z[j] = 0.f; S[j] = make_float4(0.f, 0.f, 0.f, 0.f); }

    const float4* up = reinterpret_cast<const float4*>(u_hat);
    const size_t base = (size_t)bb * 46080 + c * 3840 + t;

    for (int k = 0; k < KST; ++k) {
#pragma unroll
        for (int j = 0; j < 5; ++j) {
            const float4 u4 = up[base + k * 1280 + j * 256];
            float e;
            if (MODE) {
                float d = u4.x * Vq[j].x + u4.y * Vq[j].y + u4.z * Vq[j].z + u4.w * Vq[j].w;
                d += __shfl_xor(d, 1);
                d += __shfl_xor(d, 2);
                e = __expf(d);
            } else {
                e = 1.0f;
            }
            Z[j]   += e;
            S[j].x += e * u4.x; S[j].y += e * u4.y;
            S[j].z += e * u4.z; S[j].w += e * u4.w;
        }
    }

#pragma unroll
    for (int j = 0; j < 5; ++j) {
        float* r = &red[(t * 5 + j) * 5];
        r[0] = Z[j]; r[1] = S[j].x; r[2] = S[j].y; r[3] = S[j].z; r[4] = S[j].w;
    }
    __syncthreads();

    if (t < 40) {
        const int oo = t >> 2, qq = t & 3;
        float acc0 = 0.f, acc1 = 0.f, acc2 = 0.f, acc3 = 0.f, acc4 = 0.f;
        for (int p = (oo & 1); p < 64; p += 2) {
            const int dd = (oo - p + 70) % 10;          // even (parity matched)
            const int j  = ((dd >> 1) * 3) % 5;         // solves (p+4j)%10 == oo
            const float* r = &red[((p * 4 + qq) * 5 + j) * 5];
            acc0 += r[0]; acc1 += r[1]; acc2 += r[2]; acc3 += r[3]; acc4 += r[4];
        }
        float* o = &P[(((size_t)c * NB + bb) * 40 + t) * 5];
        o[0] = acc0; o[1] = acc1; o[2] = acc2; o[3] = acc3; o[4] = acc4;
    }
}

template<int R>   // 0: write V1=v0; 1: write V2=V1+v1; 2: write out=v2
__global__ __launch_bounds__(64)
void combine_kernel(const float* __restrict__ P, const float* __restrict__ Vprev,
                    float* __restrict__ Vnext, float* __restrict__ out) {
    const int t  = threadIdx.x;
    const int bb = blockIdx.x;
    if (t >= 40) return;
    const int oo = t >> 2, q = t & 3;

    float Z = 0.f;
    float4 S = make_float4(0.f, 0.f, 0.f, 0.f);
    for (int c = 0; c < NCH; ++c) {
        const float* r = &P[(((size_t)c * NB + bb) * 40 + t) * 5];
        Z += r[0]; S.x += r[1]; S.y += r[2]; S.z += r[3]; S.w += r[4];
    }
    const float inv = 1.0f / Z;
    const float4 s = make_float4(S.x * inv, S.y * inv, S.z * inv, S.w * inv);

    float pr = s.x * s.x + s.y * s.y + s.z * s.z + s.w * s.w;
    pr += __shfl_xor(pr, 1);
    pr += __shfl_xor(pr, 2);
    const float scale = pr / ((1.0f + pr) * sqrtf(pr + 1e-7f));
    float4 v = make_float4(s.x * scale, s.y * scale, s.z * scale, s.w * scale);

    if (R == 2) {
        *reinterpret_cast<float4*>(out + ((size_t)bb * NOUT + oo) * 16 + q * 4) = v;
    } else {
        if (R == 1) {
            const float4 Vp = *reinterpret_cast<const float4*>(
                Vprev + ((bb * NOUT + oo) * 16) + q * 4);
            v.x += Vp.x; v.y += Vp.y; v.z += Vp.z; v.w += Vp.w;
        }
        *reinterpret_cast<float4*>(Vnext + ((bb * NOUT + oo) * 16) + q * 4) = v;
    }
}

extern "C" void kernel_launch(void* const* d_in, const int* in_sizes, int n_in,
                              void* d_out, int out_size, void* d_ws, size_t ws_size,
                              hipStream_t stream) {
    const float* u = (const float*)d_in[0];
    float* out = (float*)d_out;
    float* ws  = (float*)d_ws;
    float* V1  = ws;                 // [256][10][16]
    float* V2  = ws + 40960;
    float* P   = ws + 81920;         // [NCH][256][40][5] = 614400 floats

    const dim3 pg(NB * NCH), pb(256), cg(NB), cb(64);
    pass_kernel<0><<<pg, pb, 0, stream>>>(u, nullptr, P);
    combine_kernel<0><<<cg, cb, 0, stream>>>(P, nullptr, V1, nullptr);
    pass_kernel<1><<<pg, pb, 0, stream>>>(u, V1, P);
    combine_kernel<1><<<cg, cb, 0, stream>>>(P, V1, V2, nullptr);
    pass_kernel<1><<<pg, pb, 0, stream>>>(u, V2, P);
    combine_kernel<2><<<cg, cb, 0, stream>>>(P, nullptr, nullptr, out);
}